// Round 8
// baseline (455.040 us; speedup 1.0000x reference)
//
#include <hip/hip_runtime.h>
#include <hip/hip_bf16.h>
#include <hip/hip_cooperative_groups.h>
#include <stdint.h>

namespace cg = cooperative_groups;

typedef __attribute__((ext_vector_type(4))) float f32x4;
typedef __attribute__((ext_vector_type(8))) short short8;

// ---------------- geometry ----------------
#define NB 8
#define NC 512
#define HP 66
#define WP 66
#define NPOS 32768
#define KTOT 4608
#define NKT 72           // K-tiles of 64

#define XP_ELEMS (NB*HP*WP*NC)
#define WR_ELEMS (NC*KTOT)
#define WC2_ELEMS (64*NC)
#define PROP_OFF 0
#define CLS_OFF  1179648
#define ANCH_OFF 1769472
#define A_PER_B  36864
#define TSTRIDE  4672     // floats per prep team region

__device__ __forceinline__ short bf16bits(float v) {
    __hip_bfloat16 b = __float2bfloat16(v);
    return *reinterpret_cast<short*>(&b);
}
__device__ __forceinline__ void gload16(const short* g, short* l) {
    __builtin_amdgcn_global_load_lds(
        (const __attribute__((address_space(1))) unsigned int*)g,
        (__attribute__((address_space(3))) unsigned int*)l, 16, 0, 0);
}
#define BARRIER() asm volatile("s_barrier" ::: "memory")
#define VMCNT4()  asm volatile("s_waitcnt vmcnt(4)" ::: "memory")
#define VMCNT0()  asm volatile("s_waitcnt vmcnt(0)" ::: "memory")

__device__ const float AW_T[9] = {
    181.01933598375618f, 362.03867196751236f, 724.0773439350247f,
    128.f, 256.f, 512.f,
    90.50966799187809f, 181.01933598375618f, 362.03867196751236f };
__device__ const float AH_T[9] = {
    90.50966799187809f, 181.01933598375618f, 362.03867196751236f,
    128.f, 256.f, 512.f,
    181.01933598375618f, 362.03867196751236f, 724.0773439350247f };

// ---------------- mega: prep -> gridsync -> conv+heads -> gridsync -> decode
__launch_bounds__(512, 2)
__global__ void mega(const float* __restrict__ x, const int* __restrict__ img,
                     const float* __restrict__ conv_w, const float* __restrict__ bias,
                     const float* __restrict__ cls_w, const float* __restrict__ cls_b,
                     const float* __restrict__ reg_w, const float* __restrict__ reg_b,
                     float* __restrict__ out, short* __restrict__ Xp,
                     short* __restrict__ Wr, short* __restrict__ Wc2,
                     float* __restrict__ partial) {
    extern __shared__ short lds[];
    cg::grid_group gg = cg::this_grid();
    const int tid = threadIdx.x;
    const int bid = blockIdx.x;

    // ================= PHASE 0: prep (2 teams of 256 threads) =================
    {
        const int team = tid >> 8, ttid = tid & 255;
        float* tsm = (float*)lds + team*TSTRIDE;
        float (*t65)[65] = (float(*)[65])tsm;

        // ---- input pack: 4096 jobs = 256 blocks x 8 rounds x 2 teams ----
#pragma unroll 1
        for (int r = 0; r < 8; ++r) {
            const int job = bid*16 + r*2 + team;
            const int pb = job & 63, cb = (job >> 6) & 7, b = job >> 9;
            const float* src = x + ((size_t)(b*NC + cb*64))*4096 + pb*64;
            const int w4 = ttid & 15, chb = ttid >> 4;
#pragma unroll
            for (int r2 = 0; r2 < 4; ++r2) {
                int ch = r2*16 + chb;
                float4 v = *(const float4*)(src + (size_t)ch*4096 + w4*4);
                t65[ch][w4*4 + 0] = v.x;
                t65[ch][w4*4 + 1] = v.y;
                t65[ch][w4*4 + 2] = v.z;
                t65[ch][w4*4 + 3] = v.w;
            }
            __syncthreads();
#pragma unroll
            for (int rr = 0; rr < 2; ++rr) {
                int item = ttid + rr*256;
                int pl = item >> 3, ck = item & 7;
                short8 v;
#pragma unroll
                for (int e = 0; e < 8; ++e) v[e] = bf16bits(t65[ck*8+e][pl]);
                *(short8*)&Xp[((size_t)((b*HP + pb + 1)*WP) + (pl + 1))*NC + cb*64 + ck*8] = v;
            }
            __syncthreads();
        }

        // ---- conv_w pack: 512 jobs = 256 blocks x 2 teams ----
        {
            const int o = bid*2 + team;
            const float4* src4 = (const float4*)(conv_w + (size_t)o*4608);
            float4* tsm4 = (float4*)tsm;
            for (int i = ttid; i < 1152; i += 256) tsm4[i] = src4[i];
            __syncthreads();
#pragma unroll
            for (int k = 0; k < 9; ++k)
#pragma unroll
                for (int c = 0; c < 2; ++c) {
                    int ci = ttid + c*256;
                    Wr[(size_t)o*4608 + k*512 + ci] = bf16bits(tsm[ci*9 + k]);
                }
            __syncthreads();
        }

        // ---- Wc2 pack (no LDS): 32768 items over first 64 blocks ----
        if (bid < 64) {
            int t = bid*512 + tid;
            int row = t >> 9, ci = t & 511;
            float v = 0.f;
            if (row < 18)      v = cls_w[row*NC + ci];
            else if (row < 54) v = reg_w[(row-18)*NC + ci];
            Wc2[t] = bf16bits(v);
        }
        // ---- Xp border zeros: 133120 short8 stores, grid-strided ----
        for (int idx = bid*512 + tid; idx < 133120; idx += 131072) {
            int b = idx / 16640;
            int rem = idx - b*16640;
            int r = rem >> 6, g = rem & 63;
            int h, w;
            if      (r < 66)  { h = 0;       w = r; }
            else if (r < 132) { h = 65;      w = r - 66; }
            else if (r < 196) { h = r - 131; w = 0; }
            else              { h = r - 195; w = 65; }
            short8 z = (short8){0,0,0,0,0,0,0,0};
            *(short8*)&Xp[((size_t)((b*HP + h)*WP) + w)*NC + g*8] = z;
        }
    }
    __threadfence();
    gg.sync();

    // ================= PHASE 1: conv K-loop (verified round-2/6 schedule) =====
    const int lane = tid & 63, wv = tid >> 6;
    const int wg = (bid & 7) * 32 + (bid >> 3);       // XCD swizzle (256%8==0)
    const int pbase  = (wg >> 1) * 256;
    const int cobase = (wg & 1) * 256;
    const int wm = wv >> 2, wn = wv & 3;

    const int g_data = (tid & 7) ^ ((tid >> 3) & 7);  // pre-swizzled k-group
    int abase[4], bbase[4];
#pragma unroll
    for (int q = 0; q < 4; ++q) {
        int p = pbase + q*64 + (tid >> 3);
        int b = p >> 12, h = (p >> 6) & 63, w = p & 63;
        abase[q] = ((b*HP + h)*WP + w)*NC + g_data*8;
        bbase[q] = (cobase + q*64 + (tid >> 3))*KTOT + g_data*8;
    }
    const int stoff = tid*8;

    const int l15 = lane & 15, l4 = lane >> 4, l7 = lane & 7;
    const int kidx0 = (l4 ^ l7) * 8;
    const int kidx1 = ((4 + l4) ^ l7) * 8;
    const int Aroff = wm*8192 + l15*64;
    const int Broff = 16384 + (wn>>1)*8192 + (wn&1)*4096 + l15*64;

    auto stageA = [&](int t, int hh) {
        int seg = t >> 3;
        int dh = seg / 3, dw = seg - dh*3;
        int off = (dh*WP + dw)*NC + (t & 7)*64;
        short* dst = lds + (t & 1)*32768 + hh*8192 + stoff;
        gload16(Xp + abase[hh*2+0] + off, dst);
        gload16(Xp + abase[hh*2+1] + off, dst + 4096);
    };
    auto stageB = [&](int t, int hh) {
        int off = t * 64;
        short* dst = lds + (t & 1)*32768 + 16384 + hh*8192 + stoff;
        gload16(Wr + bbase[hh*2+0] + off, dst);
        gload16(Wr + bbase[hh*2+1] + off, dst + 4096);
    };

    f32x4 acc[8][4];
#pragma unroll
    for (int i = 0; i < 8; ++i)
#pragma unroll
        for (int j = 0; j < 4; ++j) acc[i][j] = (f32x4){0.f,0.f,0.f,0.f};

    short8 af[2][2], bfr[4][2];
    auto readA = [&](int bufb, int i2) {
        const short* Ab = lds + bufb*32768 + Aroff;
#pragma unroll
        for (int ii = 0; ii < 2; ++ii) {
            af[ii][0] = *(const short8*)(Ab + (i2+ii)*1024 + kidx0);
            af[ii][1] = *(const short8*)(Ab + (i2+ii)*1024 + kidx1);
        }
    };
    auto readB = [&](int bufb) {
        const short* Bb = lds + bufb*32768 + Broff;
#pragma unroll
        for (int j = 0; j < 4; ++j) {
            bfr[j][0] = *(const short8*)(Bb + j*1024 + kidx0);
            bfr[j][1] = *(const short8*)(Bb + j*1024 + kidx1);
        }
    };
    auto mfmaQ = [&](int i2) {
        __builtin_amdgcn_s_setprio(1);
#pragma unroll
        for (int kk = 0; kk < 2; ++kk)
#pragma unroll
            for (int ii = 0; ii < 2; ++ii)
#pragma unroll
                for (int j = 0; j < 4; ++j)
                    acc[i2+ii][j] = __builtin_amdgcn_mfma_f32_16x16x32_bf16(
                        af[ii][kk], bfr[j][kk], acc[i2+ii][j], 0, 0, 0);
        __builtin_amdgcn_s_setprio(0);
    };

    // prologue
    stageB(0,0); stageB(0,1); stageA(0,0); stageA(0,1); stageB(1,0); stageB(1,1);
    VMCNT4(); BARRIER();

    for (int it = 0; it < 36; ++it) {
        const int t1 = 2*it+1, t2 = 2*it+2, t3 = 2*it+3;
        const bool s2 = (t2 < NKT), s3 = (t3 < NKT);
        readB(0); readA(0, 0);
        stageA(t1, 0);
        BARRIER(); mfmaQ(0); BARRIER();
        readA(0, 2);
        stageA(t1, 1);
        BARRIER(); mfmaQ(2); BARRIER();
        readA(0, 4);
        if (s2) stageB(t2, 0);
        BARRIER(); mfmaQ(4); BARRIER();
        readA(0, 6);
        if (s2) stageB(t2, 1);
        BARRIER(); mfmaQ(6);
        if (s2) { VMCNT4(); } else { VMCNT0(); }
        BARRIER();
        readB(1); readA(1, 0);
        if (s2) stageA(t2, 0);
        BARRIER(); mfmaQ(0); BARRIER();
        readA(1, 2);
        if (s2) stageA(t2, 1);
        BARRIER(); mfmaQ(2); BARRIER();
        readA(1, 4);
        if (s3) stageB(t3, 0);
        BARRIER(); mfmaQ(4); BARRIER();
        readA(1, 6);
        if (s3) stageB(t3, 1);
        BARRIER(); mfmaQ(6);
        if (s3) { VMCNT4(); } else { VMCNT0(); }
        BARRIER();
    }
    __syncthreads();

    // ---- ep1: bias+relu -> f_tile[256][256] bf16, XOR-swizzled
#pragma unroll
    for (int j = 0; j < 4; ++j) {
        const int ch = wn*64 + j*16 + l15;
        const float bb = bias[cobase + ch];
        const int g = ch >> 3, e = ch & 7;
#pragma unroll
        for (int i = 0; i < 8; ++i) {
#pragma unroll
            for (int r = 0; r < 4; ++r) {
                const int pos = wm*128 + i*16 + l4*4 + r;
                float v = acc[i][j][r] + bb;
                v = v > 0.f ? v : 0.f;
                const int slot = (g & 24) | ((g ^ pos) & 7);
                lds[pos*256 + slot*8 + e] = bf16bits(v);
            }
        }
    }
    __syncthreads();

    // ---- ep2: head partial GEMM M=256(pos), N=64, K=256(local ch)
    f32x4 acc2[2][4];
#pragma unroll
    for (int i2 = 0; i2 < 2; ++i2)
#pragma unroll
        for (int j2 = 0; j2 < 4; ++j2) acc2[i2][j2] = (f32x4){0.f,0.f,0.f,0.f};
    const int hbase = wv*32;
#pragma unroll
    for (int kk = 0; kk < 8; ++kk) {
        short8 b2[4];
#pragma unroll
        for (int j2 = 0; j2 < 4; ++j2)
            b2[j2] = *(const short8*)&Wc2[(size_t)(j2*16 + l15)*NC + cobase + kk*32 + l4*8];
#pragma unroll
        for (int i2 = 0; i2 < 2; ++i2) {
            const int pos = hbase + i2*16 + l15;
            const int g = kk*4 + l4;
            const int slot = (g & 24) | ((g ^ pos) & 7);
            short8 a2 = *(const short8*)&lds[pos*256 + slot*8];
#pragma unroll
            for (int j2 = 0; j2 < 4; ++j2)
                acc2[i2][j2] = __builtin_amdgcn_mfma_f32_16x16x32_bf16(
                    a2, b2[j2], acc2[i2][j2], 0, 0, 0);
        }
    }

    // ---- ep3: write partials[half][pos][64] f32
    const int half = wg & 1;
    float* pdst = partial + ((size_t)half*NPOS + pbase + hbase)*64;
#pragma unroll
    for (int i2 = 0; i2 < 2; ++i2)
#pragma unroll
        for (int j2 = 0; j2 < 4; ++j2)
#pragma unroll
            for (int r = 0; r < 4; ++r)
                pdst[(i2*16 + l4*4 + r)*64 + j2*16 + l15] = acc2[i2][j2][r];

    __threadfence();
    gg.sync();

    // ================= PHASE 2: combine + anchor decode =======================
    {
        float* sm = (float*)lds;            // [128][65]
        const int dp0 = bid * 128;
        const float4* pa = (const float4*)partial;
#pragma unroll
        for (int q = 0; q < 4; ++q) {
            int idx = tid + q*512;          // 2048 = 128 pos x 16 float4
            int pl = idx >> 4, n4 = idx & 15;
            float4 a = pa[(size_t)(dp0 + pl)*16 + n4];
            float4 b = pa[(size_t)(NPOS + dp0 + pl)*16 + n4];
            sm[pl*65 + n4*4 + 0] = a.x + b.x;
            sm[pl*65 + n4*4 + 1] = a.y + b.y;
            sm[pl*65 + n4*4 + 2] = a.z + b.z;
            sm[pl*65 + n4*4 + 3] = a.w + b.w;
        }
        __syncthreads();

        for (int item = tid; item < 1152; item += 512) {
            int pl = item / 9, a = item - pl*9;
            int p = dp0 + pl;
            int b = p >> 12, h = (p >> 6) & 63, w = p & 63;
            float c0 = sm[pl*65 + a*2 + 0] + cls_b[a*2 + 0];
            float c1 = sm[pl*65 + a*2 + 1] + cls_b[a*2 + 1];
            float r0 = sm[pl*65 + 18 + a*4 + 0] + reg_b[a*4 + 0];
            float r1 = sm[pl*65 + 18 + a*4 + 1] + reg_b[a*4 + 1];
            float r2 = sm[pl*65 + 18 + a*4 + 2] + reg_b[a*4 + 2];
            float r3 = sm[pl*65 + 18 + a*4 + 3] + reg_b[a*4 + 3];
            float aw = AW_T[a], ah = AH_T[a];
            float ax = 8.f + 16.f*w, ay = 8.f + 16.f*h;
            float px = ax + r0*aw,  py = ay + r1*ah;
            float pw = aw*__expf(r2), ph = ah*__expf(r3);
            float imw = (float)img[b*2 + 0], imh = (float)img[b*2 + 1];
            float x1 = fminf(fmaxf(px - 0.5f*pw, 0.f), imw);
            float y1 = fminf(fmaxf(py - 0.5f*ph, 0.f), imh);
            float x2 = fminf(fmaxf(px + 0.5f*pw, 0.f), imw);
            float y2 = fminf(fmaxf(py + 0.5f*ph, 0.f), imh);
            int ag = (h*64 + w)*9 + a;
            float4* prop = (float4*)(out + PROP_OFF + ((size_t)b*A_PER_B + ag)*4);
            *prop = make_float4(x1, y1, x2, y2);
            float2* cs = (float2*)(out + CLS_OFF + ((size_t)b*A_PER_B + ag)*2);
            *cs = make_float2(c0, c1);
            out[ANCH_OFF + (size_t)b*A_PER_B + ag] = 0.0f;
        }
    }
}

extern "C" void kernel_launch(void* const* d_in, const int* in_sizes, int n_in,
                              void* d_out, int out_size, void* d_ws, size_t ws_size,
                              hipStream_t stream) {
    const float* x      = (const float*)d_in[0];
    const int*   img    = (const int*)  d_in[1];
    const float* conv_w = (const float*)d_in[2];
    const float* conv_b = (const float*)d_in[3];
    const float* cls_w  = (const float*)d_in[4];
    const float* cls_b  = (const float*)d_in[5];
    const float* reg_w  = (const float*)d_in[6];
    const float* reg_b  = (const float*)d_in[7];
    float* out = (float*)d_out;

    short* Xp      = (short*)d_ws;
    short* Wr      = Xp  + XP_ELEMS;
    short* Wc2     = Wr  + WR_ELEMS;
    float* partial = (float*)(Wc2 + WC2_ELEMS);   // 2*NPOS*64 f32 = 16MB

    hipFuncSetAttribute((const void*)mega,
                        hipFuncAttributeMaxDynamicSharedMemorySize, 131072);
    void* args[] = {(void*)&x, (void*)&img, (void*)&conv_w, (void*)&conv_b,
                    (void*)&cls_w, (void*)&cls_b, (void*)&reg_w, (void*)&reg_b,
                    (void*)&out, (void*)&Xp, (void*)&Wr, (void*)&Wc2,
                    (void*)&partial};
    hipLaunchCooperativeKernel((const void*)mega, dim3(256), dim3(512),
                               args, 131072, stream);
}

// Round 9
// 265.466 us; speedup vs baseline: 1.7141x; 1.7141x over previous
//
#include <hip/hip_runtime.h>
#include <hip/hip_bf16.h>
#include <stdint.h>

typedef __attribute__((ext_vector_type(4))) float f32x4;
typedef __attribute__((ext_vector_type(16))) float f32x16;
typedef __attribute__((ext_vector_type(8))) short short8;

// ---------------- geometry ----------------
#define NB 8
#define NC 512
#define HP 66
#define WP 66
#define NPOS 32768
#define KTOT 4608
#define NKT 72           // K-tiles of 64

#define XP_ELEMS (NB*HP*WP*NC)
#define WR_ELEMS (NC*KTOT)
#define WC2_ELEMS (64*NC)
#define PROP_OFF 0
#define CLS_OFF  1179648
#define ANCH_OFF 1769472
#define A_PER_B  36864

__device__ __forceinline__ short bf16bits(float v) {
    __hip_bfloat16 b = __float2bfloat16(v);
    return *reinterpret_cast<short*>(&b);
}
__device__ __forceinline__ void gload16(const short* g, short* l) {
    __builtin_amdgcn_global_load_lds(
        (const __attribute__((address_space(1))) unsigned int*)g,
        (__attribute__((address_space(3))) unsigned int*)l, 16, 0, 0);
}
#define BARRIER() asm volatile("s_barrier" ::: "memory")
#define VMCNT4()  asm volatile("s_waitcnt vmcnt(4)" ::: "memory")
#define VMCNT0()  asm volatile("s_waitcnt vmcnt(0)" ::: "memory")

// ---------------- fused prep: input pack + weight packs + zero fills --------
// grid 5256: [0,4096) input; [4096,4608) conv_w; [4608,4736) Wc2; rest border
__global__ void prep_all(const float* __restrict__ x, const float* __restrict__ conv_w,
                         const float* __restrict__ cls_w, const float* __restrict__ reg_w,
                         short* __restrict__ Wr, short* __restrict__ Wc2,
                         short* __restrict__ Xp) {
    __shared__ float smem[4608];
    const int bid = blockIdx.x, tid = threadIdx.x;
    if (bid < 4096) {
        // ---- NCHW f32 -> padded NHWC bf16; float4 loads (G13) ----
        float (*t)[65] = (float(*)[65])smem;
        const int pb = bid & 63, cb = (bid >> 6) & 7, b = bid >> 9;
        const float* src = x + ((size_t)(b*NC + cb*64))*4096 + pb*64;
        const int w4 = tid & 15, chb = tid >> 4;       // 16 ch-rows per pass
#pragma unroll
        for (int r = 0; r < 4; ++r) {
            int ch = r*16 + chb;
            float4 v = *(const float4*)(src + (size_t)ch*4096 + w4*4);
            t[ch][w4*4 + 0] = v.x;
            t[ch][w4*4 + 1] = v.y;
            t[ch][w4*4 + 2] = v.z;
            t[ch][w4*4 + 3] = v.w;
        }
        __syncthreads();
#pragma unroll
        for (int rr = 0; rr < 2; ++rr) {
            int item = tid + rr*256;
            int pl = item >> 3, ck = item & 7;
            short8 v;
#pragma unroll
            for (int e = 0; e < 8; ++e) v[e] = bf16bits(t[ck*8+e][pl]);
            *(short8*)&Xp[((size_t)((b*HP + pb + 1)*WP) + (pl + 1))*NC + cb*64 + ck*8] = v;
        }
    } else if (bid < 4608) {
        // ---- conv_w OIHW f32 -> Wr[co][k*512+ci]; float4 staging loads ----
        const int o = bid - 4096;
        const float4* src4 = (const float4*)(conv_w + (size_t)o*4608);
        float4* smem4 = (float4*)smem;
        for (int i = tid; i < 1152; i += 256) smem4[i] = src4[i];
        __syncthreads();
#pragma unroll
        for (int k = 0; k < 9; ++k)
#pragma unroll
            for (int c = 0; c < 2; ++c) {
                int ci = tid + c*256;
                Wr[(size_t)o*4608 + k*512 + ci] = bf16bits(smem[ci*9 + k]);
            }
    } else {
        const int m = bid - 4608;
        if (m < 128) {
            int t = m*256 + tid;
            int row = t >> 9, ci = t & 511;
            float v = 0.f;
            if (row < 18)      v = cls_w[row*NC + ci];
            else if (row < 54) v = reg_w[(row-18)*NC + ci];
            Wc2[t] = bf16bits(v);
        } else {
            int idx = (m-128)*256 + tid;          // < 133120
            int b = idx / 16640;
            int rem = idx - b*16640;
            int r = rem >> 6, g = rem & 63;
            int h, w;
            if      (r < 66)  { h = 0;       w = r; }
            else if (r < 132) { h = 65;      w = r - 66; }
            else if (r < 196) { h = r - 131; w = 0; }
            else              { h = r - 195; w = 65; }
            short8 z = (short8){0,0,0,0,0,0,0,0};
            *(short8*)&Xp[((size_t)((b*HP + h)*WP) + w)*NC + g*8] = z;
        }
    }
}

// ---------------- conv: 256^2-tile 8-phase, 32x32x16 MFMA -------------------
// Same staging/vmcnt schedule & swizzle as the verified round-6/7 kernel;
// only the MFMA shape and fragment reads change (16x16x32 -> 32x32x16).
// Epilogue: acc -> swizzled LDS f_tile[256pos][256ch] bf16 -> head partial
// GEMM (M=256,N=64,K=256, 16x16x32) -> f32 partials[half][pos][64] in ws.
__launch_bounds__(512, 2)
__global__ void conv_fused(const short* __restrict__ Xp, const short* __restrict__ Wr,
                           const float* __restrict__ bias, const short* __restrict__ Wc2,
                           float* __restrict__ partial) {
    extern __shared__ short lds[];
    const int tid = threadIdx.x;
    const int lane = tid & 63, wv = tid >> 6;
    const int bid = blockIdx.x;
    const int wg = (bid & 7) * 32 + (bid >> 3);       // XCD swizzle (256%8==0)
    const int pbase  = (wg >> 1) * 256;
    const int cobase = (wg & 1) * 256;
    const int wm = wv >> 2, wn = wv & 3;

    const int g_data = (tid & 7) ^ ((tid >> 3) & 7);  // pre-swizzled k-group
    int abase[4], bbase[4];
#pragma unroll
    for (int q = 0; q < 4; ++q) {
        int p = pbase + q*64 + (tid >> 3);
        int b = p >> 12, h = (p >> 6) & 63, w = p & 63;
        abase[q] = ((b*HP + h)*WP + w)*NC + g_data*8;
        bbase[q] = (cobase + q*64 + (tid >> 3))*KTOT + g_data*8;
    }
    const int stoff = tid*8;

    const int l15 = lane & 15, l4 = lane >> 4, l7 = lane & 7;
    const int l31 = lane & 31, ls5 = lane >> 5;

    auto stageA = [&](int t, int hh) {
        int seg = t >> 3;
        int dh = seg / 3, dw = seg - dh*3;
        int off = (dh*WP + dw)*NC + (t & 7)*64;
        short* dst = lds + (t & 1)*32768 + hh*8192 + stoff;
        gload16(Xp + abase[hh*2+0] + off, dst);
        gload16(Xp + abase[hh*2+1] + off, dst + 4096);
    };
    auto stageB = [&](int t, int hh) {
        int off = t * 64;
        short* dst = lds + (t & 1)*32768 + 16384 + hh*8192 + stoff;
        gload16(Wr + bbase[hh*2+0] + off, dst);
        gload16(Wr + bbase[hh*2+1] + off, dst + 4096);
    };

    // 32x32 accumulators: wave tile 128x64 = 4 row-tiles x 2 col-tiles
    f32x16 acc32[4][2];
#pragma unroll
    for (int i = 0; i < 4; ++i)
#pragma unroll
        for (int j = 0; j < 2; ++j) acc32[i][j] = (f32x16)(0.f);

    short8 af32[2][2];   // [ri within pair][k-slice within half]
    short8 bf32[2][4];   // [cj][k-slice 0..3]

    // A frag (32x32x16): row = l31, k = ls5*8 + e; LDS slot = (s*2+ls5)^l7
    auto readA32 = [&](int bufb, int rb, int sb) {
        const short* Ab = lds + bufb*32768 + (wm*128 + l31)*64;
#pragma unroll
        for (int ri = 0; ri < 2; ++ri)
#pragma unroll
            for (int sp = 0; sp < 2; ++sp) {
                const int s = sb + sp;
                const int slot = (s*2 + ls5) ^ l7;
                af32[ri][sp] = *(const short8*)(Ab + (rb + ri)*2048 + slot*8);
            }
    };
    auto readB32 = [&](int bufb, int sb) {
        const short* Bb = lds + bufb*32768 + 16384 + (wn*64 + l31)*64;
#pragma unroll
        for (int cj = 0; cj < 2; ++cj)
#pragma unroll
            for (int sp = 0; sp < 2; ++sp) {
                const int s = sb + sp;
                const int slot = (s*2 + ls5) ^ l7;
                bf32[cj][s] = *(const short8*)(Bb + cj*2048 + slot*8);
            }
    };
    auto mfma32 = [&](int rb, int sb) {
        __builtin_amdgcn_s_setprio(1);
#pragma unroll
        for (int sp = 0; sp < 2; ++sp)
#pragma unroll
            for (int ri = 0; ri < 2; ++ri)
#pragma unroll
                for (int cj = 0; cj < 2; ++cj)
                    acc32[rb+ri][cj] = __builtin_amdgcn_mfma_f32_32x32x16_bf16(
                        af32[ri][sp], bf32[cj][sb+sp], acc32[rb+ri][cj], 0, 0, 0);
        __builtin_amdgcn_s_setprio(0);
    };

    // prologue (identical staging/vmcnt to verified schedule)
    stageB(0,0); stageB(0,1); stageA(0,0); stageA(0,1); stageB(1,0); stageB(1,1);
    VMCNT4(); BARRIER();

    for (int it = 0; it < 36; ++it) {
        const int t1 = 2*it+1, t2 = 2*it+2, t3 = 2*it+3;
        const bool s2 = (t2 < NKT), s3 = (t3 < NKT);
        // tile 2it on buf0
        readB32(0, 0); readA32(0, 0, 0);
        stageA(t1, 0);
        BARRIER(); mfma32(0, 0); BARRIER();
        readB32(0, 2); readA32(0, 0, 2);
        stageA(t1, 1);
        BARRIER(); mfma32(0, 2); BARRIER();
        readA32(0, 2, 0);
        if (s2) stageB(t2, 0);
        BARRIER(); mfma32(2, 0); BARRIER();
        readA32(0, 2, 2);
        if (s2) stageB(t2, 1);
        BARRIER(); mfma32(2, 2);
        if (s2) { VMCNT4(); } else { VMCNT0(); }
        BARRIER();
        // tile 2it+1 on buf1
        readB32(1, 0); readA32(1, 0, 0);
        if (s2) stageA(t2, 0);
        BARRIER(); mfma32(0, 0); BARRIER();
        readB32(1, 2); readA32(1, 0, 2);
        if (s2) stageA(t2, 1);
        BARRIER(); mfma32(0, 2); BARRIER();
        readA32(1, 2, 0);
        if (s3) stageB(t3, 0);
        BARRIER(); mfma32(2, 0); BARRIER();
        readA32(1, 2, 2);
        if (s3) stageB(t3, 1);
        BARRIER(); mfma32(2, 2);
        if (s3) { VMCNT4(); } else { VMCNT0(); }
        BARRIER();
    }
    __syncthreads();

    // ---- ep1: bias+relu -> f_tile[256][256] bf16, XOR-swizzled
    // 32x32 D frag: col = l31, row = (e&3) + 8*(e>>2) + 4*ls5
#pragma unroll
    for (int cj = 0; cj < 2; ++cj) {
        const int ch = wn*64 + cj*32 + l31;           // local ch 0..255
        const float bb = bias[cobase + ch];
        const int g = ch >> 3, e8 = ch & 7;
#pragma unroll
        for (int ri = 0; ri < 4; ++ri) {
#pragma unroll
            for (int e = 0; e < 16; ++e) {
                const int pos = wm*128 + ri*32 + (e & 3) + 8*(e >> 2) + 4*ls5;
                float v = acc32[ri][cj][e] + bb;
                v = v > 0.f ? v : 0.f;
                const int slot = (g & 24) | ((g ^ pos) & 7);
                lds[pos*256 + slot*8 + e8] = bf16bits(v);
            }
        }
    }
    __syncthreads();

    // ---- ep2: head partial GEMM M=256(pos), N=64, K=256 (16x16x32)
    f32x4 acc2[2][4];
#pragma unroll
    for (int i2 = 0; i2 < 2; ++i2)
#pragma unroll
        for (int j2 = 0; j2 < 4; ++j2) acc2[i2][j2] = (f32x4){0.f,0.f,0.f,0.f};
    const int hbase = wv*32;
#pragma unroll
    for (int kk = 0; kk < 8; ++kk) {
        short8 b2[4];
#pragma unroll
        for (int j2 = 0; j2 < 4; ++j2)
            b2[j2] = *(const short8*)&Wc2[(size_t)(j2*16 + l15)*NC + cobase + kk*32 + l4*8];
#pragma unroll
        for (int i2 = 0; i2 < 2; ++i2) {
            const int pos = hbase + i2*16 + l15;
            const int g = kk*4 + l4;
            const int slot = (g & 24) | ((g ^ pos) & 7);
            short8 a2 = *(const short8*)&lds[pos*256 + slot*8];
#pragma unroll
            for (int j2 = 0; j2 < 4; ++j2)
                acc2[i2][j2] = __builtin_amdgcn_mfma_f32_16x16x32_bf16(
                    a2, b2[j2], acc2[i2][j2], 0, 0, 0);
        }
    }

    // ---- ep3: write partials[half][pos][64] f32
    const int half = wg & 1;
    float* pdst = partial + ((size_t)half*NPOS + pbase + hbase)*64;
#pragma unroll
    for (int i2 = 0; i2 < 2; ++i2)
#pragma unroll
        for (int j2 = 0; j2 < 4; ++j2)
#pragma unroll
            for (int r = 0; r < 4; ++r)
                pdst[(i2*16 + l4*4 + r)*64 + j2*16 + l15] = acc2[i2][j2][r];
}

// ---------------- combine: sum K-halves + anchor decode + anchors zeros -----
__device__ const float AW_T[9] = {
    181.01933598375618f, 362.03867196751236f, 724.0773439350247f,
    128.f, 256.f, 512.f,
    90.50966799187809f, 181.01933598375618f, 362.03867196751236f };
__device__ const float AH_T[9] = {
    90.50966799187809f, 181.01933598375618f, 362.03867196751236f,
    128.f, 256.f, 512.f,
    181.01933598375618f, 362.03867196751236f, 724.0773439350247f };

__launch_bounds__(256)
__global__ void combine_decode(const float* __restrict__ partial,
                               const float* __restrict__ cls_b, const float* __restrict__ reg_b,
                               const int* __restrict__ img, float* __restrict__ out) {
    __shared__ float sm[64*65];
    const int tid = threadIdx.x;
    const int p0 = blockIdx.x * 64;
    const float4* pa = (const float4*)partial;
#pragma unroll
    for (int q = 0; q < 4; ++q) {
        int idx = tid + q*256;                 // 1024 = 64 pos x 16 float4
        int pl = idx >> 4, n4 = idx & 15;
        float4 a = pa[(size_t)(p0 + pl)*16 + n4];
        float4 b = pa[(size_t)(NPOS + p0 + pl)*16 + n4];
        sm[pl*65 + n4*4 + 0] = a.x + b.x;
        sm[pl*65 + n4*4 + 1] = a.y + b.y;
        sm[pl*65 + n4*4 + 2] = a.z + b.z;
        sm[pl*65 + n4*4 + 3] = a.w + b.w;
    }
    __syncthreads();

    for (int item = tid; item < 576; item += 256) {
        int pl = item / 9, a = item - pl*9;
        int p = p0 + pl;
        int b = p >> 12, h = (p >> 6) & 63, w = p & 63;
        float c0 = sm[pl*65 + a*2 + 0] + cls_b[a*2 + 0];
        float c1 = sm[pl*65 + a*2 + 1] + cls_b[a*2 + 1];
        float r0 = sm[pl*65 + 18 + a*4 + 0] + reg_b[a*4 + 0];
        float r1 = sm[pl*65 + 18 + a*4 + 1] + reg_b[a*4 + 1];
        float r2 = sm[pl*65 + 18 + a*4 + 2] + reg_b[a*4 + 2];
        float r3 = sm[pl*65 + 18 + a*4 + 3] + reg_b[a*4 + 3];
        float aw = AW_T[a], ah = AH_T[a];
        float ax = 8.f + 16.f*w, ay = 8.f + 16.f*h;
        float px = ax + r0*aw,  py = ay + r1*ah;
        float pw = aw*__expf(r2), ph = ah*__expf(r3);
        float imw = (float)img[b*2 + 0], imh = (float)img[b*2 + 1];
        float x1 = fminf(fmaxf(px - 0.5f*pw, 0.f), imw);
        float y1 = fminf(fmaxf(py - 0.5f*ph, 0.f), imh);
        float x2 = fminf(fmaxf(px + 0.5f*pw, 0.f), imw);
        float y2 = fminf(fmaxf(py + 0.5f*ph, 0.f), imh);
        int ag = (h*64 + w)*9 + a;
        float4* prop = (float4*)(out + PROP_OFF + ((size_t)b*A_PER_B + ag)*4);
        *prop = make_float4(x1, y1, x2, y2);
        float2* cs = (float2*)(out + CLS_OFF + ((size_t)b*A_PER_B + ag)*2);
        *cs = make_float2(c0, c1);
        out[ANCH_OFF + (size_t)b*A_PER_B + ag] = 0.0f;   // anchors_ignore = 0
    }
}

extern "C" void kernel_launch(void* const* d_in, const int* in_sizes, int n_in,
                              void* d_out, int out_size, void* d_ws, size_t ws_size,
                              hipStream_t stream) {
    const float* x      = (const float*)d_in[0];
    const int*   img    = (const int*)  d_in[1];
    const float* conv_w = (const float*)d_in[2];
    const float* conv_b = (const float*)d_in[3];
    const float* cls_w  = (const float*)d_in[4];
    const float* cls_b  = (const float*)d_in[5];
    const float* reg_w  = (const float*)d_in[6];
    const float* reg_b  = (const float*)d_in[7];
    float* out = (float*)d_out;

    short* Xp      = (short*)d_ws;
    short* Wr      = Xp  + XP_ELEMS;
    short* Wc2     = Wr  + WR_ELEMS;
    float* partial = (float*)(Wc2 + WC2_ELEMS);   // 2*NPOS*64 f32 = 16MB

    prep_all<<<5256, 256, 0, stream>>>(x, conv_w, cls_w, reg_w, Wr, Wc2, Xp);

    hipFuncSetAttribute((const void*)conv_fused,
                        hipFuncAttributeMaxDynamicSharedMemorySize, 131072);
    conv_fused<<<256, 512, 131072, stream>>>(Xp, Wr, conv_b, Wc2, partial);
    combine_decode<<<NPOS/64, 256, 0, stream>>>(partial, cls_b, reg_b, img, out);
}

// Round 10
// 248.153 us; speedup vs baseline: 1.8337x; 1.0698x over previous
//
#include <hip/hip_runtime.h>
#include <hip/hip_bf16.h>
#include <stdint.h>

typedef __attribute__((ext_vector_type(4))) float f32x4;
typedef __attribute__((ext_vector_type(8))) short short8;

// ---------------- geometry ----------------
#define NB 8
#define NC 512
#define HP 66
#define WP 66
#define NPOS 32768
#define KTOT 4608
#define NKT 72           // K-tiles of 64

#define XP_ELEMS (NB*HP*WP*NC)
#define WR_ELEMS (NC*KTOT)
#define WC2_ELEMS (64*NC)
#define PROP_OFF 0
#define CLS_OFF  1179648
#define ANCH_OFF 1769472
#define A_PER_B  36864

__device__ __forceinline__ short bf16bits(float v) {
    __hip_bfloat16 b = __float2bfloat16(v);
    return *reinterpret_cast<short*>(&b);
}
__device__ __forceinline__ void gload16(const short* g, short* l) {
    __builtin_amdgcn_global_load_lds(
        (const __attribute__((address_space(1))) unsigned int*)g,
        (__attribute__((address_space(3))) unsigned int*)l, 16, 0, 0);
}
#define BARRIER() asm volatile("s_barrier" ::: "memory")
#define VMCNT4()  asm volatile("s_waitcnt vmcnt(4)" ::: "memory")
#define VMCNT0()  asm volatile("s_waitcnt vmcnt(0)" ::: "memory")

// ---------------- fused prep: input pack + weight packs + zero fills --------
// grid 5256: [0,4096) input; [4096,4608) conv_w; [4608,4736) Wc2; rest border
__global__ void prep_all(const float* __restrict__ x, const float* __restrict__ conv_w,
                         const float* __restrict__ cls_w, const float* __restrict__ reg_w,
                         short* __restrict__ Wr, short* __restrict__ Wc2,
                         short* __restrict__ Xp) {
    __shared__ float smem[4608];
    const int bid = blockIdx.x, tid = threadIdx.x;
    if (bid < 4096) {
        // ---- NCHW f32 -> padded NHWC bf16; float4 loads (G13) ----
        float (*t)[65] = (float(*)[65])smem;
        const int pb = bid & 63, cb = (bid >> 6) & 7, b = bid >> 9;
        const float* src = x + ((size_t)(b*NC + cb*64))*4096 + pb*64;
        const int w4 = tid & 15, chb = tid >> 4;       // 16 ch-rows per pass
#pragma unroll
        for (int r = 0; r < 4; ++r) {
            int ch = r*16 + chb;
            float4 v = *(const float4*)(src + (size_t)ch*4096 + w4*4);
            t[ch][w4*4 + 0] = v.x;
            t[ch][w4*4 + 1] = v.y;
            t[ch][w4*4 + 2] = v.z;
            t[ch][w4*4 + 3] = v.w;
        }
        __syncthreads();
#pragma unroll
        for (int rr = 0; rr < 2; ++rr) {
            int item = tid + rr*256;
            int pl = item >> 3, ck = item & 7;
            short8 v;
#pragma unroll
            for (int e = 0; e < 8; ++e) v[e] = bf16bits(t[ck*8+e][pl]);
            *(short8*)&Xp[((size_t)((b*HP + pb + 1)*WP) + (pl + 1))*NC + cb*64 + ck*8] = v;
        }
    } else if (bid < 4608) {
        // ---- conv_w OIHW f32 -> Wr[co][k*512+ci]; float4 staging loads ----
        const int o = bid - 4096;
        const float4* src4 = (const float4*)(conv_w + (size_t)o*4608);
        float4* smem4 = (float4*)smem;
        for (int i = tid; i < 1152; i += 256) smem4[i] = src4[i];
        __syncthreads();
#pragma unroll
        for (int k = 0; k < 9; ++k)
#pragma unroll
            for (int c = 0; c < 2; ++c) {
                int ci = tid + c*256;
                Wr[(size_t)o*4608 + k*512 + ci] = bf16bits(smem[ci*9 + k]);
            }
    } else {
        const int m = bid - 4608;
        if (m < 128) {
            int t = m*256 + tid;
            int row = t >> 9, ci = t & 511;
            float v = 0.f;
            if (row < 18)      v = cls_w[row*NC + ci];
            else if (row < 54) v = reg_w[(row-18)*NC + ci];
            Wc2[t] = bf16bits(v);
        } else {
            int idx = (m-128)*256 + tid;          // < 133120
            int b = idx / 16640;
            int rem = idx - b*16640;
            int r = rem >> 6, g = rem & 63;
            int h, w;
            if      (r < 66)  { h = 0;       w = r; }
            else if (r < 132) { h = 65;      w = r - 66; }
            else if (r < 196) { h = r - 131; w = 0; }
            else              { h = r - 195; w = 65; }
            short8 z = (short8){0,0,0,0,0,0,0,0};
            *(short8*)&Xp[((size_t)((b*HP + h)*WP) + w)*NC + g*8] = z;
        }
    }
}

// ---------------- conv: 256^2-tile, 4 merged phases/K-tile, 16x16x32 --------
// Identical staging order, vmcnt placement, swizzle, and fragment layout to
// the verified round-6/7 kernel; only the intermediate barriers are halved
// (8 -> 4 per K-tile): each region = {16 ds_read + 4 gload} then 32 MFMA.
// Epilogue: acc -> swizzled LDS f_tile[256pos][256ch] bf16 -> head partial
// GEMM (M=256,N=64,K=256) -> f32 partials[half][pos][64] in ws.
__launch_bounds__(512, 2)
__global__ void conv_fused(const short* __restrict__ Xp, const short* __restrict__ Wr,
                           const float* __restrict__ bias, const short* __restrict__ Wc2,
                           float* __restrict__ partial) {
    extern __shared__ short lds[];
    const int tid = threadIdx.x;
    const int lane = tid & 63, wv = tid >> 6;
    const int bid = blockIdx.x;
    const int wg = (bid & 7) * 32 + (bid >> 3);       // XCD swizzle (256%8==0)
    const int pbase  = (wg >> 1) * 256;
    const int cobase = (wg & 1) * 256;
    const int wm = wv >> 2, wn = wv & 3;

    const int g_data = (tid & 7) ^ ((tid >> 3) & 7);  // pre-swizzled k-group
    int abase[4], bbase[4];
#pragma unroll
    for (int q = 0; q < 4; ++q) {
        int p = pbase + q*64 + (tid >> 3);
        int b = p >> 12, h = (p >> 6) & 63, w = p & 63;
        abase[q] = ((b*HP + h)*WP + w)*NC + g_data*8;
        bbase[q] = (cobase + q*64 + (tid >> 3))*KTOT + g_data*8;
    }
    const int stoff = tid*8;

    const int l15 = lane & 15, l4 = lane >> 4, l7 = lane & 7;
    const int kidx0 = (l4 ^ l7) * 8;
    const int kidx1 = ((4 + l4) ^ l7) * 8;
    const int Aroff = wm*8192 + l15*64;
    const int Broff = 16384 + (wn>>1)*8192 + (wn&1)*4096 + l15*64;

    auto stageA = [&](int t, int hh) {
        int seg = t >> 3;
        int dh = seg / 3, dw = seg - dh*3;
        int off = (dh*WP + dw)*NC + (t & 7)*64;
        short* dst = lds + (t & 1)*32768 + hh*8192 + stoff;
        gload16(Xp + abase[hh*2+0] + off, dst);
        gload16(Xp + abase[hh*2+1] + off, dst + 4096);
    };
    auto stageB = [&](int t, int hh) {
        int off = t * 64;
        short* dst = lds + (t & 1)*32768 + 16384 + hh*8192 + stoff;
        gload16(Wr + bbase[hh*2+0] + off, dst);
        gload16(Wr + bbase[hh*2+1] + off, dst + 4096);
    };

    f32x4 acc[8][4];
#pragma unroll
    for (int i = 0; i < 8; ++i)
#pragma unroll
        for (int j = 0; j < 4; ++j) acc[i][j] = (f32x4){0.f,0.f,0.f,0.f};

    short8 af[4][2], bfr[4][2];
    auto readA4 = [&](int bufb, int i2b) {
        const short* Ab = lds + bufb*32768 + Aroff;
#pragma unroll
        for (int ii = 0; ii < 4; ++ii) {
            af[ii][0] = *(const short8*)(Ab + (i2b+ii)*1024 + kidx0);
            af[ii][1] = *(const short8*)(Ab + (i2b+ii)*1024 + kidx1);
        }
    };
    auto readB = [&](int bufb) {
        const short* Bb = lds + bufb*32768 + Broff;
#pragma unroll
        for (int j = 0; j < 4; ++j) {
            bfr[j][0] = *(const short8*)(Bb + j*1024 + kidx0);
            bfr[j][1] = *(const short8*)(Bb + j*1024 + kidx1);
        }
    };
    auto mfmaH = [&](int i2b) {
        __builtin_amdgcn_s_setprio(1);
#pragma unroll
        for (int kk = 0; kk < 2; ++kk)
#pragma unroll
            for (int ii = 0; ii < 4; ++ii)
#pragma unroll
                for (int j = 0; j < 4; ++j)
                    acc[i2b+ii][j] = __builtin_amdgcn_mfma_f32_16x16x32_bf16(
                        af[ii][kk], bfr[j][kk], acc[i2b+ii][j], 0, 0, 0);
        __builtin_amdgcn_s_setprio(0);
    };

    // prologue (identical to verified schedule)
    stageB(0,0); stageB(0,1); stageA(0,0); stageA(0,1); stageB(1,0); stageB(1,1);
    VMCNT4(); BARRIER();

    for (int it = 0; it < 36; ++it) {
        const int t1 = 2*it+1, t2 = 2*it+2, t3 = 2*it+3;
        const bool s2 = (t2 < NKT), s3 = (t3 < NKT);
        // tile 2it (buf0)
        readB(0); readA4(0, 0);
        stageA(t1, 0); stageA(t1, 1);
        BARRIER(); mfmaH(0); BARRIER();
        readA4(0, 4);
        if (s2) { stageB(t2, 0); stageB(t2, 1); }
        BARRIER(); mfmaH(4);
        if (s2) { VMCNT4(); } else { VMCNT0(); }
        BARRIER();
        // tile 2it+1 (buf1)
        readB(1); readA4(1, 0);
        if (s2) { stageA(t2, 0); stageA(t2, 1); }
        BARRIER(); mfmaH(0); BARRIER();
        readA4(1, 4);
        if (s3) { stageB(t3, 0); stageB(t3, 1); }
        BARRIER(); mfmaH(4);
        if (s3) { VMCNT4(); } else { VMCNT0(); }
        BARRIER();
    }
    __syncthreads();

    // ---- ep1: bias+relu -> f_tile[256][256] bf16, XOR-swizzled (128KB LDS)
    // D frag: col = l15 (ch), row = l4*4 + r (pos)
#pragma unroll
    for (int j = 0; j < 4; ++j) {
        const int ch = wn*64 + j*16 + l15;            // local ch 0..255
        const float bb = bias[cobase + ch];
        const int g = ch >> 3, e = ch & 7;
#pragma unroll
        for (int i = 0; i < 8; ++i) {
#pragma unroll
            for (int r = 0; r < 4; ++r) {
                const int pos = wm*128 + i*16 + l4*4 + r;
                float v = acc[i][j][r] + bb;
                v = v > 0.f ? v : 0.f;
                const int slot = (g & 24) | ((g ^ pos) & 7);
                lds[pos*256 + slot*8 + e] = bf16bits(v);
            }
        }
    }
    __syncthreads();

    // ---- ep2: head partial GEMM M=256(pos), N=64, K=256(local ch)
    f32x4 acc2[2][4];
#pragma unroll
    for (int i2 = 0; i2 < 2; ++i2)
#pragma unroll
        for (int j2 = 0; j2 < 4; ++j2) acc2[i2][j2] = (f32x4){0.f,0.f,0.f,0.f};
    const int hbase = wv*32;
#pragma unroll
    for (int kk = 0; kk < 8; ++kk) {
        short8 b2[4];
#pragma unroll
        for (int j2 = 0; j2 < 4; ++j2)
            b2[j2] = *(const short8*)&Wc2[(size_t)(j2*16 + l15)*NC + cobase + kk*32 + l4*8];
#pragma unroll
        for (int i2 = 0; i2 < 2; ++i2) {
            const int pos = hbase + i2*16 + l15;
            const int g = kk*4 + l4;
            const int slot = (g & 24) | ((g ^ pos) & 7);
            short8 a2 = *(const short8*)&lds[pos*256 + slot*8];
#pragma unroll
            for (int j2 = 0; j2 < 4; ++j2)
                acc2[i2][j2] = __builtin_amdgcn_mfma_f32_16x16x32_bf16(
                    a2, b2[j2], acc2[i2][j2], 0, 0, 0);
        }
    }

    // ---- ep3: write partials[half][pos][64] f32
    const int half = wg & 1;
    float* pdst = partial + ((size_t)half*NPOS + pbase + hbase)*64;
#pragma unroll
    for (int i2 = 0; i2 < 2; ++i2)
#pragma unroll
        for (int j2 = 0; j2 < 4; ++j2)
#pragma unroll
            for (int r = 0; r < 4; ++r)
                pdst[(i2*16 + l4*4 + r)*64 + j2*16 + l15] = acc2[i2][j2][r];
}

// ---------------- combine: sum K-halves + anchor decode + anchors zeros -----
__device__ const float AW_T[9] = {
    181.01933598375618f, 362.03867196751236f, 724.0773439350247f,
    128.f, 256.f, 512.f,
    90.50966799187809f, 181.01933598375618f, 362.03867196751236f };
__device__ const float AH_T[9] = {
    90.50966799187809f, 181.01933598375618f, 362.03867196751236f,
    128.f, 256.f, 512.f,
    181.01933598375618f, 362.03867196751236f, 724.0773439350247f };

__launch_bounds__(256)
__global__ void combine_decode(const float* __restrict__ partial,
                               const float* __restrict__ cls_b, const float* __restrict__ reg_b,
                               const int* __restrict__ img, float* __restrict__ out) {
    __shared__ float sm[64*65];
    const int tid = threadIdx.x;
    const int p0 = blockIdx.x * 64;
    const float4* pa = (const float4*)partial;
#pragma unroll
    for (int q = 0; q < 4; ++q) {
        int idx = tid + q*256;                 // 1024 = 64 pos x 16 float4
        int pl = idx >> 4, n4 = idx & 15;
        float4 a = pa[(size_t)(p0 + pl)*16 + n4];
        float4 b = pa[(size_t)(NPOS + p0 + pl)*16 + n4];
        sm[pl*65 + n4*4 + 0] = a.x + b.x;
        sm[pl*65 + n4*4 + 1] = a.y + b.y;
        sm[pl*65 + n4*4 + 2] = a.z + b.z;
        sm[pl*65 + n4*4 + 3] = a.w + b.w;
    }
    __syncthreads();

    for (int item = tid; item < 576; item += 256) {
        int pl = item / 9, a = item - pl*9;
        int p = p0 + pl;
        int b = p >> 12, h = (p >> 6) & 63, w = p & 63;
        float c0 = sm[pl*65 + a*2 + 0] + cls_b[a*2 + 0];
        float c1 = sm[pl*65 + a*2 + 1] + cls_b[a*2 + 1];
        float r0 = sm[pl*65 + 18 + a*4 + 0] + reg_b[a*4 + 0];
        float r1 = sm[pl*65 + 18 + a*4 + 1] + reg_b[a*4 + 1];
        float r2 = sm[pl*65 + 18 + a*4 + 2] + reg_b[a*4 + 2];
        float r3 = sm[pl*65 + 18 + a*4 + 3] + reg_b[a*4 + 3];
        float aw = AW_T[a], ah = AH_T[a];
        float ax = 8.f + 16.f*w, ay = 8.f + 16.f*h;
        float px = ax + r0*aw,  py = ay + r1*ah;
        float pw = aw*__expf(r2), ph = ah*__expf(r3);
        float imw = (float)img[b*2 + 0], imh = (float)img[b*2 + 1];
        float x1 = fminf(fmaxf(px - 0.5f*pw, 0.f), imw);
        float y1 = fminf(fmaxf(py - 0.5f*ph, 0.f), imh);
        float x2 = fminf(fmaxf(px + 0.5f*pw, 0.f), imw);
        float y2 = fminf(fmaxf(py + 0.5f*ph, 0.f), imh);
        int ag = (h*64 + w)*9 + a;
        float4* prop = (float4*)(out + PROP_OFF + ((size_t)b*A_PER_B + ag)*4);
        *prop = make_float4(x1, y1, x2, y2);
        float2* cs = (float2*)(out + CLS_OFF + ((size_t)b*A_PER_B + ag)*2);
        *cs = make_float2(c0, c1);
        out[ANCH_OFF + (size_t)b*A_PER_B + ag] = 0.0f;   // anchors_ignore = 0
    }
}

extern "C" void kernel_launch(void* const* d_in, const int* in_sizes, int n_in,
                              void* d_out, int out_size, void* d_ws, size_t ws_size,
                              hipStream_t stream) {
    const float* x      = (const float*)d_in[0];
    const int*   img    = (const int*)  d_in[1];
    const float* conv_w = (const float*)d_in[2];
    const float* conv_b = (const float*)d_in[3];
    const float* cls_w  = (const float*)d_in[4];
    const float* cls_b  = (const float*)d_in[5];
    const float* reg_w  = (const float*)d_in[6];
    const float* reg_b  = (const float*)d_in[7];
    float* out = (float*)d_out;

    short* Xp      = (short*)d_ws;
    short* Wr      = Xp  + XP_ELEMS;
    short* Wc2     = Wr  + WR_ELEMS;
    float* partial = (float*)(Wc2 + WC2_ELEMS);   // 2*NPOS*64 f32 = 16MB

    prep_all<<<5256, 256, 0, stream>>>(x, conv_w, cls_w, reg_w, Wr, Wc2, Xp);

    hipFuncSetAttribute((const void*)conv_fused,
                        hipFuncAttributeMaxDynamicSharedMemorySize, 131072);
    conv_fused<<<256, 512, 131072, stream>>>(Xp, Wr, conv_b, Wc2, partial);
    combine_decode<<<NPOS/64, 256, 0, stream>>>(partial, cls_b, reg_b, img, out);
}